// Round 1
// 580.576 us; speedup vs baseline: 1.0607x; 1.0607x over previous
//
#include <hip/hip_runtime.h>
#include <hip/hip_fp16.h>

#define NN 100000
#define EC 6400000
#define ED 400000
#define BN_EPS 1e-5f
#define NSB ((NN + 255) >> 8)    // 391 buckets of 256 nodes
#define NCH 256                  // edge chunks per graph
#define CSR_CAP 19200            // LDS CSR build capacity (mean 16384 + slack)
#define CHUNK_OF(E) (((((E) + NCH - 1) / NCH) + 3) & ~3)   // 4-aligned chunk

// ---------------- fused preprocessing (R11 bodies, branched grids) ------------
// 18 dispatches -> 10: the ~150us unexplained residual matches ~8us/dispatch
// launch/drain gaps; eid work also now overlaps eic work within each kernel.

// grid = 2*NCH + 32: [0,NCH) eic hist, [NCH,2NCH) eid hist, rest = prep_misc
__global__ __launch_bounds__(1024)
void pre_hist_prep(const int* __restrict__ eic, const int* __restrict__ eid,
                   int* __restrict__ bhist_c, int* __restrict__ bhist_d,
                   const float* __restrict__ x, const float* __restrict__ W1l,
                   const float* __restrict__ W1r, float* __restrict__ xp,
                   __half* __restrict__ xp16,
                   float* __restrict__ W1lp, float* __restrict__ W1rp) {
    int blk = blockIdx.x;
    if (blk < 2 * NCH) {
        const int* ei = (blk < NCH) ? eic : eid;
        int E = (blk < NCH) ? EC : ED;
        int* bhist = (blk < NCH) ? bhist_c : bhist_d;
        int k = (blk < NCH) ? blk : blk - NCH;
        __shared__ int h[NSB];
        for (int i = threadIdx.x; i < NSB; i += 1024) h[i] = 0;
        __syncthreads();
        int chunk = CHUNK_OF(E);
        int beg = k * chunk, end = min(E, beg + chunk);
        for (int e = beg + threadIdx.x * 4; e < end; e += 1024 * 4) {
            int4 d4 = *(const int4*)&ei[E + e];
            atomicAdd(&h[d4.x >> 8], 1);
            atomicAdd(&h[d4.y >> 8], 1);
            atomicAdd(&h[d4.z >> 8], 1);
            atomicAdd(&h[d4.w >> 8], 1);
        }
        __syncthreads();
        for (int i = threadIdx.x; i < NSB; i += 1024) bhist[i * NCH + k] = h[i];
    } else {
        // prep: x -> f32 padded [NN,8] + fp16 copy; W1 -> padded 8x8
        int pb = blk - 2 * NCH;
        int t = pb * 1024 + threadIdx.x;
        if (t < 64) {
            int f = t >> 3, k = t & 7;
            W1lp[t] = (k < 5) ? W1l[f * 5 + k] : 0.f;
            W1rp[t] = (k < 5) ? W1r[f * 5 + k] : 0.f;
        }
        for (int idx = t; idx < NN * 8; idx += 32 * 1024) {
            int f = idx & 7, i = idx >> 3;
            float v = (f < 5) ? x[i * 5 + f] : 0.f;
            xp[idx] = v;
            xp16[idx] = __float2half(v);
        }
    }
}

// grid = 2*NSB: per-bucket exclusive scan over NCH chunk counts, both graphs
__global__ __launch_bounds__(256)
void row_scan2(int* __restrict__ bhist_c, int* __restrict__ total_c,
               int* __restrict__ bhist_d, int* __restrict__ total_d) {
    int blk = blockIdx.x;
    int* row = (blk < NSB) ? (bhist_c + blk * NCH)
                           : (bhist_d + (blk - NSB) * NCH);
    int* total = (blk < NSB) ? total_c : total_d;
    int bb = (blk < NSB) ? blk : blk - NSB;
    __shared__ int wsum[4];
    int lane = threadIdx.x & 63, w = threadIdx.x >> 6;
    int v = row[threadIdx.x];
    int x = v;
    #pragma unroll
    for (int sh = 1; sh < 64; sh <<= 1) { int y = __shfl_up(x, sh); if (lane >= sh) x += y; }
    if (lane == 63) wsum[w] = x;
    __syncthreads();
    int wb = 0;
    #pragma unroll
    for (int j = 0; j < 4; ++j) if (j < w) wb += wsum[j];
    row[threadIdx.x] = wb + x - v;
    if (threadIdx.x == 255) total[bb] = wb + x;
}

// one block: zero stats (replaces memset) + bucket bases for both graphs
__global__ void base2(const int* __restrict__ total_c, int* __restrict__ bbase_c,
                      const int* __restrict__ total_d, int* __restrict__ bbase_d,
                      float* __restrict__ stats) {
    for (int i = threadIdx.x; i < 5 * 256; i += 256) stats[i] = 0.f;
    __shared__ int wsum[4];
    __shared__ int carry;
    int lane = threadIdx.x & 63, w = threadIdx.x >> 6;
    for (int which = 0; which < 2; ++which) {
        const int* gt = which ? total_d : total_c;
        int* bb = which ? bbase_d : bbase_c;
        if (threadIdx.x == 0) carry = 0;
        __syncthreads();
        for (int s = 0; s < NSB; s += 256) {
            int idx = s + threadIdx.x;
            int v = (idx < NSB) ? gt[idx] : 0;
            int x = v;
            #pragma unroll
            for (int sh = 1; sh < 64; sh <<= 1) { int y = __shfl_up(x, sh); if (lane >= sh) x += y; }
            if (lane == 63) wsum[w] = x;
            __syncthreads();
            int wb = 0;
            #pragma unroll
            for (int j = 0; j < 4; ++j) if (j < w) wb += wsum[j];
            int all = wsum[0] + wsum[1] + wsum[2] + wsum[3];
            if (idx < NSB) bb[idx] = carry + wb + x - v;
            __syncthreads();
            if (threadIdx.x == 0) carry += all;
            __syncthreads();
        }
    }
}

// grid = 2*NCH: scatter into per-(chunk,bucket) regions, both graphs
__global__ __launch_bounds__(1024)
void scatter2(const int* __restrict__ eic, const int* __restrict__ eid,
              const int* __restrict__ bhist_c, const int* __restrict__ bbase_c,
              unsigned* __restrict__ packed_c,
              const int* __restrict__ bhist_d, const int* __restrict__ bbase_d,
              unsigned* __restrict__ packed_d) {
    int blk = blockIdx.x;
    const int* ei = (blk < NCH) ? eic : eid;
    int E = (blk < NCH) ? EC : ED;
    const int* bhist = (blk < NCH) ? bhist_c : bhist_d;
    const int* bbase = (blk < NCH) ? bbase_c : bbase_d;
    unsigned* packed = (blk < NCH) ? packed_c : packed_d;
    int k = (blk < NCH) ? blk : blk - NCH;
    __shared__ int cur[NSB];
    for (int b = threadIdx.x; b < NSB; b += 1024)
        cur[b] = bbase[b] + bhist[b * NCH + k];
    __syncthreads();
    int chunk = CHUNK_OF(E);
    int beg = k * chunk, end = min(E, beg + chunk);
    for (int e = beg + threadIdx.x * 4; e < end; e += 1024 * 4) {
        int4 s4 = *(const int4*)&ei[e];
        int4 d4 = *(const int4*)&ei[E + e];
        { int p = atomicAdd(&cur[d4.x >> 8], 1); packed[p] = (unsigned)s4.x | ((unsigned)(d4.x & 255) << 17); }
        { int p = atomicAdd(&cur[d4.y >> 8], 1); packed[p] = (unsigned)s4.y | ((unsigned)(d4.y & 255) << 17); }
        { int p = atomicAdd(&cur[d4.z >> 8], 1); packed[p] = (unsigned)s4.z | ((unsigned)(d4.z & 255) << 17); }
        { int p = atomicAdd(&cur[d4.w >> 8], 1); packed[p] = (unsigned)s4.w | ((unsigned)(d4.w & 255) << 17); }
    }
}

// grid = 2*NSB: exact per-node CSR via LDS, both graphs
__global__ __launch_bounds__(256)
void csr2(const unsigned* __restrict__ packed_c, const int* __restrict__ bbase_c,
          const int* __restrict__ total_c, int* __restrict__ csr_c,
          int* __restrict__ offs_c, int* __restrict__ deg_c, float* __restrict__ inv_c,
          const unsigned* __restrict__ packed_d, const int* __restrict__ bbase_d,
          const int* __restrict__ total_d, int* __restrict__ csr_d,
          int* __restrict__ offs_d, int* __restrict__ deg_d, float* __restrict__ inv_d) {
    int blk = blockIdx.x;
    const unsigned* packed = (blk < NSB) ? packed_c : packed_d;
    const int* bbase = (blk < NSB) ? bbase_c : bbase_d;
    const int* total = (blk < NSB) ? total_c : total_d;
    int* csr  = (blk < NSB) ? csr_c : csr_d;
    int* offs = (blk < NSB) ? offs_c : offs_d;
    int* deg  = (blk < NSB) ? deg_c : deg_d;
    float* inv = (blk < NSB) ? inv_c : inv_d;
    int b = (blk < NSB) ? blk : blk - NSB;

    __shared__ int h[256];
    __shared__ int loff[256];
    __shared__ int ws2[4];
    __shared__ int ebuf[CSR_CAP];
    int ebeg = bbase[b], ecnt = total[b];
    int node0 = b << 8;
    int nn = min(256, NN - node0);
    h[threadIdx.x] = 0;
    __syncthreads();
    for (int e = threadIdx.x; e < ecnt; e += 256)
        atomicAdd(&h[packed[ebeg + e] >> 17], 1);
    __syncthreads();
    {
        int lane = threadIdx.x & 63, w = threadIdx.x >> 6;
        int v = h[threadIdx.x], x = v;
        #pragma unroll
        for (int sh = 1; sh < 64; sh <<= 1) { int y = __shfl_up(x, sh); if (lane >= sh) x += y; }
        if (lane == 63) ws2[w] = x;
        __syncthreads();
        int wb = 0;
        #pragma unroll
        for (int j = 0; j < 4; ++j) if (j < w) wb += ws2[j];
        int excl = wb + x - v;
        loff[threadIdx.x] = excl;
        if (threadIdx.x < nn) {
            int node = node0 + threadIdx.x;
            offs[node] = ebeg + excl;
            deg[node]  = v;
            inv[node]  = 1.0f / (float)(v > 1 ? v : 1);
        }
    }
    __syncthreads();
    if (ecnt <= CSR_CAP) {
        for (int e = threadIdx.x; e < ecnt; e += 256) {
            unsigned u = packed[ebeg + e];
            int p = atomicAdd(&loff[u >> 17], 1);
            ebuf[p] = (int)(u & 0x1FFFF);
        }
        __syncthreads();
        for (int e = threadIdx.x; e < ecnt; e += 256) csr[ebeg + e] = ebuf[e];
    } else {
        for (int e = threadIdx.x; e < ecnt; e += 256) {
            unsigned u = packed[ebeg + e];
            int p = atomicAdd(&loff[u >> 17], 1);
            csr[ebeg + p] = (int)(u & 0x1FFFF);
        }
    }
}

// ---------------- fused SAGE layer v7 ----------------------------------------
// R12: edge loop widened 8 -> 32 edges per group-iteration. Each lane loads 4
// consecutive csr dwords (independent, back-to-back issue: ONE csr-latency wait
// per 32 edges) then 4 independent row gathers (compiler stages vmcnt waits).
// Serial-chain units per node: ceil(d/8) -> ceil(d/32). Masked slots gather row
// 0 (broadcast line, ~free) instead of garbage addresses. BN scale/shift folded
// into weights (y = sum_k acim*wls + h*wrs + dnz*Bl + Br) to keep VGPRs <= 64.
#define ACC8(RV, M) do { \
    float2 q0 = __half22float2(*(const __half2*)&RV.x); \
    float2 q1 = __half22float2(*(const __half2*)&RV.y); \
    float2 q2 = __half22float2(*(const __half2*)&RV.z); \
    float2 q3 = __half22float2(*(const __half2*)&RV.w); \
    a0 = fmaf(q0.x, M, a0); a1 = fmaf(q0.y, M, a1); \
    a2 = fmaf(q1.x, M, a2); a3 = fmaf(q1.y, M, a3); \
    a4 = fmaf(q2.x, M, a4); a5 = fmaf(q2.y, M, a5); \
    a6 = fmaf(q3.x, M, a6); a7 = fmaf(q3.y, M, a7); \
} while (0)

template<bool APPLY_BN>
__global__ __launch_bounds__(256)
void sage_layer8(const float* __restrict__ hin,       // f32 rows (self-term)
                 const __half* __restrict__ hin16,    // fp16 rows (gather)
                 const float* __restrict__ stats_in,  // [k*16]=sum, [(8+k)*16]=sumsq
                 const float* __restrict__ gin, const float* __restrict__ bin,
                 const int* __restrict__ offs, const int* __restrict__ deg,
                 const int* __restrict__ csr, const float* __restrict__ inv,
                 const float* __restrict__ Wl, const float* __restrict__ Wr,
                 float* __restrict__ hout, __half* __restrict__ hout16,
                 float* __restrict__ stats_out) {
    __shared__ float bl[16];
    int tid = threadIdx.x;
    if (tid < 16) bl[tid] = 0.f;
    __syncthreads();
    int wave = tid >> 6, lane = tid & 63, g = lane >> 3, f = lane & 7;

    // fold BN affine into weights: 16 persistent regs + 2 scalars (was 32)
    float wls[8], wrs[8];
    float Bl = 0.f, Br = 0.f;
    #pragma unroll
    for (int k = 0; k < 8; ++k) {
        float w_l = Wl[f * 8 + k], w_r = Wr[f * 8 + k];
        float sck = 1.f, shk = 0.f;
        if constexpr (APPLY_BN) {
            float m = stats_in[k * 16] * (1.f / NN);
            float v = stats_in[(8 + k) * 16] * (1.f / NN) - m * m;
            float is = rsqrtf(v + BN_EPS);
            sck = gin[k] * is;
            shk = bin[k] - m * sck;
        }
        wls[k] = sck * w_l;
        wrs[k] = sck * w_r;
        Bl = fmaf(shk, w_l, Bl);
        Br = fmaf(shk, w_r, Br);
    }

    float acc_r = 0.f, acc_r2 = 0.f;
    const int stride = gridDim.x * 32;            // blocks * 4 waves * 8 nodes
    for (int i0 = (blockIdx.x * 4 + wave) * 8; i0 < NN; i0 += stride) {
        int i = i0 + g;
        int ic = min(i, NN - 1);
        bool ok = (i < NN);
        int d = ok ? deg[ic] : 0;
        int o = offs[ic];
        float im = inv[ic];
        const float4* hp = (const float4*)(hin + (size_t)ic * 8);   // hoisted self row
        float4 h0 = hp[0];
        float4 h1 = hp[1];
        float a0 = 0, a1 = 0, a2 = 0, a3 = 0, a4 = 0, a5 = 0, a6 = 0, a7 = 0;
        for (int b = 0; b < d; b += 32) {         // divergent per group: exec-masked
            int e = b + f * 4;                    // this lane's 4-edge slot
            const int* cp = csr + o + e;          // <=31 over-read: csr +64 padded
            int c0 = cp[0], c1 = cp[1], c2 = cp[2], c3 = cp[3];
            bool k0 = (e < d), k1 = (e + 1 < d), k2 = (e + 2 < d), k3 = (e + 3 < d);
            unsigned s0 = k0 ? ((unsigned)c0 & 0x1FFFFu) : 0u;   // masked -> row 0 (bcast)
            unsigned s1 = k1 ? ((unsigned)c1 & 0x1FFFFu) : 0u;
            unsigned s2 = k2 ? ((unsigned)c2 & 0x1FFFFu) : 0u;
            unsigned s3 = k3 ? ((unsigned)c3 & 0x1FFFFu) : 0u;
            uint4 r0 = *(const uint4*)(hin16 + (size_t)s0 * 8);  // 4 independent 16B gathers
            uint4 r1 = *(const uint4*)(hin16 + (size_t)s1 * 8);
            uint4 r2 = *(const uint4*)(hin16 + (size_t)s2 * 8);
            uint4 r3 = *(const uint4*)(hin16 + (size_t)s3 * 8);
            float m0 = k0 ? 1.f : 0.f;
            float m1 = k1 ? 1.f : 0.f;
            float m2 = k2 ? 1.f : 0.f;
            float m3 = k3 ? 1.f : 0.f;
            ACC8(r0, m0);
            ACC8(r1, m1);
            ACC8(r2, m2);
            ACC8(r3, m3);
        }
        #pragma unroll
        for (int msk = 1; msk < 8; msk <<= 1) {   // group-wide sums, all lanes
            a0 += __shfl_xor(a0, msk); a1 += __shfl_xor(a1, msk);
            a2 += __shfl_xor(a2, msk); a3 += __shfl_xor(a3, msk);
            a4 += __shfl_xor(a4, msk); a5 += __shfl_xor(a5, msk);
            a6 += __shfl_xor(a6, msk); a7 += __shfl_xor(a7, msk);
        }
        float dnz = (d > 0) ? 1.f : 0.f;          // BN shift only if node has neighbors
        float hk[8] = { h0.x, h0.y, h0.z, h0.w, h1.x, h1.y, h1.z, h1.w };
        float ac[8] = { a0, a1, a2, a3, a4, a5, a6, a7 };
        float y = fmaf(dnz, Bl, Br);
        #pragma unroll
        for (int k = 0; k < 8; ++k) {
            y = fmaf(ac[k] * im, wls[k], y);
            y = fmaf(hk[k], wrs[k], y);
        }
        float n2 = y * y;
        n2 += __shfl_xor(n2, 1);
        n2 += __shfl_xor(n2, 2);
        n2 += __shfl_xor(n2, 4);
        float z = y / fmaxf(sqrtf(n2), 1e-12f);
        float r = fmaxf(z, 0.f);
        r = ok ? r : 0.f;
        if (ok) {
            hout[(size_t)i * 8 + f] = r;                   // f32 row (exact)
            hout16[(size_t)i * 8 + f] = __float2half(r);   // fp16 row (gather copy)
        }
        acc_r += r;
        acc_r2 += r * r;
    }
    atomicAdd(&bl[f], acc_r);
    atomicAdd(&bl[8 + f], acc_r2);
    __syncthreads();
    if (tid < 16) atomicAdd(&stats_out[tid * 16], bl[tid]);   // 1 cache line per feature
}

__global__ void apply_bn_out(const float* __restrict__ hin,
                             const float* __restrict__ stats,
                             const float* __restrict__ g, const float* __restrict__ b,
                             float* __restrict__ out) {
    int t = blockIdx.x * blockDim.x + threadIdx.x;
    if (t >= NN * 8) return;
    int f = t & 7;
    float m = stats[f * 16] * (1.0f / NN);
    float v = stats[(8 + f) * 16] * (1.0f / NN) - m * m;
    float sc = g[f] * rsqrtf(v + BN_EPS);
    float sh = b[f] - m * sc;
    out[t] = fmaf(hin[t], sc, sh);
}

// ---------------- launch ----------------

static inline char* bump(char*& p, size_t bytes) {
    char* r = p;
    p += (bytes + 255) & ~(size_t)255;
    return r;
}

extern "C" void kernel_launch(void* const* d_in, const int* in_sizes, int n_in,
                              void* d_out, int out_size, void* d_ws, size_t ws_size,
                              hipStream_t stream) {
    const float* x   = (const float*)d_in[0];
    const int* eic   = (const int*)d_in[1];
    const int* eid   = (const int*)d_in[2];
    const float* W1l = (const float*)d_in[3];
    const float* W1r = (const float*)d_in[4];
    const float* W2l = (const float*)d_in[5];
    const float* W2r = (const float*)d_in[6];
    const float* W3l = (const float*)d_in[7];
    const float* W3r = (const float*)d_in[8];
    const float* W4l = (const float*)d_in[9];
    const float* W4r = (const float*)d_in[10];
    const float* g1 = (const float*)d_in[11];
    const float* b1 = (const float*)d_in[12];
    const float* g2 = (const float*)d_in[13];
    const float* b2 = (const float*)d_in[14];
    const float* g3 = (const float*)d_in[15];
    const float* b3 = (const float*)d_in[16];
    const float* g4 = (const float*)d_in[17];
    const float* b4 = (const float*)d_in[18];
    float* out = (float*)d_out;

    char* p = (char*)d_ws;
    float* stats   = (float*)bump(p, 5 * 256 * 4);   // zeroed by base2 each call
    int*   bhist_c = (int*)  bump(p, (size_t)NSB * NCH * 4);
    int*   bhist_d = (int*)  bump(p, (size_t)NSB * NCH * 4);
    int*   total_c = (int*)  bump(p, NSB * 4);
    int*   bbase_c = (int*)  bump(p, NSB * 4);
    int*   total_d = (int*)  bump(p, NSB * 4);
    int*   bbase_d = (int*)  bump(p, NSB * 4);
    int*   offs_c  = (int*)  bump(p, NN * 4);
    int*   deg_c   = (int*)  bump(p, NN * 4);
    float* inv_c   = (float*)bump(p, NN * 4);
    int*   offs_d  = (int*)  bump(p, NN * 4);
    int*   deg_d   = (int*)  bump(p, NN * 4);
    float* inv_d   = (float*)bump(p, NN * 4);
    int*   csr_c   = (int*)  bump(p, ((size_t)EC + 64) * 4);   // +64 over-read pad
    int*   csr_d   = (int*)  bump(p, ((size_t)ED + 64) * 4);
    float* xp32    = (float*)bump(p, (size_t)NN * 8 * 4);
    __half* xp16   = (__half*)bump(p, (size_t)NN * 8 * 2);
    float* W1lp    = (float*)bump(p, 64 * 4);
    float* W1rp    = (float*)bump(p, 64 * 4);
    unsigned* packed_d = (unsigned*)bump(p, (size_t)ED * 4);
    // packed_c dead after csr2; overlay activation ping-pong (f32 + fp16)
    char* pc = p;
    unsigned* packed_c = (unsigned*)bump(p, (size_t)EC * 4);
    char* pr = pc;
    float*  r_a   = (float*) bump(pr, (size_t)NN * 8 * 4);
    float*  r_b   = (float*) bump(pr, (size_t)NN * 8 * 4);
    __half* h16_a = (__half*)bump(pr, (size_t)NN * 8 * 2);
    __half* h16_b = (__half*)bump(pr, (size_t)NN * 8 * 2);
    (void)ws_size; (void)in_sizes; (void)n_in; (void)out_size;

    // 10 dispatches total (was 18)
    pre_hist_prep<<<2 * NCH + 32, 1024, 0, stream>>>(
        eic, eid, bhist_c, bhist_d, x, W1l, W1r, xp32, xp16, W1lp, W1rp);
    row_scan2<<<2 * NSB, 256, 0, stream>>>(bhist_c, total_c, bhist_d, total_d);
    base2<<<1, 256, 0, stream>>>(total_c, bbase_c, total_d, bbase_d, stats);
    scatter2<<<2 * NCH, 1024, 0, stream>>>(
        eic, eid, bhist_c, bbase_c, packed_c, bhist_d, bbase_d, packed_d);
    csr2<<<2 * NSB, 256, 0, stream>>>(
        packed_c, bbase_c, total_c, csr_c, offs_c, deg_c, inv_c,
        packed_d, bbase_d, total_d, csr_d, offs_d, deg_d, inv_d);

    const int LB = 2048;   // 8192 waves x 8 nodes/wave per grid-iteration
    sage_layer8<false><<<LB, 256, 0, stream>>>(
        xp32, xp16, nullptr, nullptr, nullptr,
        offs_c, deg_c, csr_c, inv_c, W1lp, W1rp, r_a, h16_a, stats + 0);
    sage_layer8<true><<<LB, 256, 0, stream>>>(
        r_a, h16_a, stats + 0, g1, b1,
        offs_c, deg_c, csr_c, inv_c, W4l, W4r, r_b, h16_b, stats + 256);
    sage_layer8<true><<<LB, 256, 0, stream>>>(
        r_b, h16_b, stats + 256, g2, b2,
        offs_d, deg_d, csr_d, inv_d, W2l, W2r, r_a, h16_a, stats + 512);
    sage_layer8<true><<<LB, 256, 0, stream>>>(
        r_a, h16_a, stats + 512, g3, b3,
        offs_c, deg_c, csr_c, inv_c, W3l, W3r, r_b, h16_b, stats + 768);
    sage_layer8<true><<<LB, 256, 0, stream>>>(
        r_b, h16_b, stats + 768, g4, b4,
        offs_c, deg_c, csr_c, inv_c, W3l, W3r, r_a, h16_a, stats + 1024);
    apply_bn_out<<<(NN * 8 + 255) / 256, 256, 0, stream>>>(r_a, stats + 1024, g4, b4, out);
}